// Round 1
// 470.414 us; speedup vs baseline: 1.0239x; 1.0239x over previous
//
#include <hip/hip_runtime.h>

#define N_ROWS 100000
#define M_NBR  12
#define C_DIM  64
#define F_DIM  41
#define E_TOT  (N_ROWS * M_NBR)

// ---------------------------------------------------------------------------
// Kernel A: s_e = (softplus(x_e @ W1 + b1) . w2[:,0] + b2[0]) * c
//
// Restructured vs previous version:
//  - x row lives in 41 VGPRs (copied once from LDS in a prologue), so the
//    hot k-loop contains ONLY s_loads (w1 rows, K$-resident) + v_fmac.
//    No ds_read in the loop -> no mixed SMEM/DS lgkmcnt(0) drains; s_load
//    latency hides under the 82-cycle FMA run of the previous row.
//  - k-loop fully unrolled so x[k] is statically indexed (VGPRs, not scratch).
//  - LDS halved to 21 KB via two-phase staging -> occupancy becomes
//    VGPR-limited (~5 waves/SIMD = 20 waves/CU) instead of LDS-limited (12).
//    The barriers between phases also pin the prologue ds_reads so the
//    compiler cannot sink them back into the compute loop.
// ---------------------------------------------------------------------------
__global__ __launch_bounds__(256) void edge_mlp_kernel(
    const float* __restrict__ nbr_fea,   // [E, F]
    const float* __restrict__ w1,        // [F, F]
    const float* __restrict__ b1,        // [F]
    const float* __restrict__ w2,        // [F, 9]
    const float* __restrict__ b2,        // [9]
    float* __restrict__ s_out)           // [E]
{
    __shared__ float lx[128 * F_DIM];    // 20992 B

    const int tid  = threadIdx.x;
    const long base = (long)blockIdx.x * 256;
    int rem = (int)((long)E_TOT - base);
    const int nedge = rem < 256 ? rem : 256;

    float x[F_DIM];

    // ---- phase 0: stage rows [0,128), threads 0..127 copy their row to regs
    {
        const int cnt = nedge < 128 ? nedge : 128;
        const float* gx = nbr_fea + base * F_DIM;
        const int totf  = cnt * F_DIM;
        const int tot4  = totf >> 2;                 // 16B-aligned (base%256==0)
        const float4* g4 = (const float4*)gx;
        float4* l4 = (float4*)lx;
        for (int i = tid; i < tot4; i += 256) l4[i] = g4[i];
        for (int i = (tot4 << 2) + tid; i < totf; i += 256) lx[i] = gx[i];
        __syncthreads();
        if (tid < cnt) {
            #pragma unroll
            for (int k = 0; k < F_DIM; ++k) x[k] = lx[tid * F_DIM + k];  // stride 41: conflict-free
        }
        __syncthreads();
    }
    // ---- phase 1: stage rows [128,256), threads 128..255 copy to regs
    {
        const int cnt = nedge - 128 < 0 ? 0 : nedge - 128;
        const float* gx = nbr_fea + (base + 128) * F_DIM;   // +20992 B: 16B-aligned
        const int totf  = cnt * F_DIM;
        const int tot4  = totf >> 2;
        const float4* g4 = (const float4*)gx;
        float4* l4 = (float4*)lx;
        for (int i = tid; i < tot4; i += 256) l4[i] = g4[i];
        for (int i = (tot4 << 2) + tid; i < totf; i += 256) lx[i] = gx[i];
        __syncthreads();
        if (tid >= 128 && (tid - 128) < cnt) {
            #pragma unroll
            for (int k = 0; k < F_DIM; ++k) x[k] = lx[(tid - 128) * F_DIM + k];
        }
        __syncthreads();   // LDS fence: prologue ds_reads cannot sink past this
    }

    if (tid < nedge) {
        float h[F_DIM];
        #pragma unroll
        for (int j = 0; j < F_DIM; ++j) h[j] = b1[j];          // scalar loads

        #pragma unroll
        for (int k = 0; k < F_DIM; ++k) {                      // FULL unroll: x[k] static
            const float xk = x[k];
            const float* wrow = w1 + k * F_DIM;                // uniform addr -> s_load
            #pragma unroll
            for (int j = 0; j < F_DIM; ++j) h[j] = fmaf(xk, wrow[j], h[j]);
        }

        float acc = b2[0];
        #pragma unroll
        for (int j = 0; j < F_DIM; ++j) {
            float v = h[j];
            float sp = fmaxf(v, 0.0f) + __logf(1.0f + __expf(-fabsf(v)));
            acc = fmaf(sp, w2[j * 9], acc);                    // w2 col 0, scalar loads
        }
        s_out[base + tid] = acc * (0.28209479177387814f / 12.0f);
    }
}

// ---------------------------------------------------------------------------
// Kernel B1: afT = atom_fea @ (tp_w / 8).  Transform commutes with the
// gather-sum (linearity), so apply it ONCE over N instead of per-edge-sum.
// Row values read via uniform addresses (s_load); T column per-lane in VGPRs.
// ---------------------------------------------------------------------------
__global__ __launch_bounds__(256) void atom_transform_kernel(
    const float* __restrict__ atom_fea,  // [N, C]
    const float* __restrict__ tp_w,      // [C, C]
    float* __restrict__ afT)             // [N, C]
{
    const int tid = threadIdx.x;
    const int c   = tid & 63;
    const int wv  = tid >> 6;

    float Tc[64];
    #pragma unroll
    for (int k = 0; k < 64; ++k) Tc[k] = tp_w[k * 64 + c] * 0.125f;  // coalesced

    const int row0 = blockIdx.x * 64 + wv * 16;
    for (int i = 0; i < 16; ++i) {
        int r = row0 + i;                       // wave-uniform
        if (r >= N_ROWS) break;
        const float* ar = atom_fea + (long)r * C_DIM;   // uniform -> s_load
        float o = 0.0f;
        #pragma unroll
        for (int k = 0; k < 64; ++k) o = fmaf(ar[k], Tc[k], o);
        afT[(long)r * C_DIM + c] = o;                   // coalesced
    }
}

// ---------------------------------------------------------------------------
// Kernel B2: out[r][:] = sum_j s_rj * afT[idx_rj][:].  Pure gather + 12 FMA,
// float4 per lane, 4 rows in flight per wave, no LDS.
// ---------------------------------------------------------------------------
__global__ __launch_bounds__(256) void gather_kernel(
    const float* __restrict__ afT,       // [N, C]
    const int*   __restrict__ nbr_idx,   // [N, M]
    const float* __restrict__ s,         // [E]
    float* __restrict__ out)             // [N, C]
{
    const int tid  = threadIdx.x;
    const int lane = tid & 63;
    const int wv   = tid >> 6;
    const int q    = lane >> 4;          // row-in-chunk 0..3
    const int c4   = (lane & 15) * 4;    // channel offset

    const int row0 = blockIdx.x * 32 + wv * 8;   // 8 rows per wave (N = 3125*32)

    #pragma unroll
    for (int ch = 0; ch < 2; ++ch) {
        int r = row0 + ch * 4 + q;
        const int*   ir = nbr_idx + r * M_NBR;
        const float* sr = s       + r * M_NBR;
        float4 acc = make_float4(0.f, 0.f, 0.f, 0.f);
        #pragma unroll
        for (int j = 0; j < M_NBR; ++j) {
            int   idx = ir[j];
            float sv  = sr[j];
            const float4 a = *(const float4*)(afT + (long)idx * C_DIM + c4);
            acc.x = fmaf(sv, a.x, acc.x);
            acc.y = fmaf(sv, a.y, acc.y);
            acc.z = fmaf(sv, a.z, acc.z);
            acc.w = fmaf(sv, a.w, acc.w);
        }
        *(float4*)(out + (long)r * C_DIM + c4) = acc;   // coalesced
    }
}

// ---------------------------------------------------------------------------
// Fallback (ws too small for afT): fused gather + LDS-epilogue transform.
// ---------------------------------------------------------------------------
__global__ __launch_bounds__(256) void gather_transform_kernel(
    const float* __restrict__ atom_fea,
    const int*   __restrict__ nbr_idx,
    const float* __restrict__ s,
    const float* __restrict__ tp_w,
    float* __restrict__ out)
{
    __shared__ float accL[64 * C_DIM];
    const int tid = threadIdx.x;
    const int c  = tid & 63;
    const int rq = tid >> 6;

    float Tc[64];
    #pragma unroll
    for (int k = 0; k < 64; ++k) Tc[k] = tp_w[k * 64 + c] * 0.125f;

    const int row0 = blockIdx.x * 64;
    for (int i = 0; i < 16; ++i) {
        int r = row0 + rq * 16 + i;
        float a = 0.0f;
        if (r < N_ROWS) {
            const int*   ir = nbr_idx + (long)r * M_NBR;
            const float* sr = s       + (long)r * M_NBR;
            #pragma unroll
            for (int j = 0; j < M_NBR; ++j)
                a = fmaf(sr[j], atom_fea[(long)ir[j] * C_DIM + c], a);
        }
        accL[(rq * 16 + i) * C_DIM + c] = a;
    }
    __syncthreads();
    for (int i = 0; i < 16; ++i) {
        int rl = rq * 16 + i;
        int r  = row0 + rl;
        if (r >= N_ROWS) continue;
        const float* ar = accL + rl * C_DIM;
        float o = 0.0f;
        #pragma unroll
        for (int k = 0; k < 64; ++k) o = fmaf(ar[k], Tc[k], o);
        out[(long)r * C_DIM + c] = o;
    }
}

extern "C" void kernel_launch(void* const* d_in, const int* in_sizes, int n_in,
                              void* d_out, int out_size, void* d_ws, size_t ws_size,
                              hipStream_t stream) {
    const float* atom_fea = (const float*)d_in[0];
    const float* nbr_fea  = (const float*)d_in[1];
    const int*   nbr_idx  = (const int*)  d_in[2];
    // d_in[3] = pos : dead (only the constant l=0 SH channel couples)
    const float* w1   = (const float*)d_in[4];
    const float* b1   = (const float*)d_in[5];
    const float* w2   = (const float*)d_in[6];
    const float* b2   = (const float*)d_in[7];
    const float* tp_w = (const float*)d_in[8];

    float* s   = (float*)d_ws;                       // 4.8 MB
    float* out = (float*)d_out;

    const int blocksA = (E_TOT + 255) / 256;
    edge_mlp_kernel<<<blocksA, 256, 0, stream>>>(nbr_fea, w1, b1, w2, b2, s);

    const size_t sBytes   = (size_t)E_TOT * sizeof(float);          // 4,800,000 (16B-mult)
    const size_t afTBytes = (size_t)N_ROWS * C_DIM * sizeof(float); // 25.6 MB

    if (ws_size >= sBytes + afTBytes) {
        float* afT = (float*)((char*)d_ws + sBytes);
        const int blocksT = (N_ROWS + 63) / 64;
        atom_transform_kernel<<<blocksT, 256, 0, stream>>>(atom_fea, tp_w, afT);
        const int blocksG = N_ROWS / 32;             // 3125, exact
        gather_kernel<<<blocksG, 256, 0, stream>>>(afT, nbr_idx, s, out);
    } else {
        const int blocksB = (N_ROWS + 63) / 64;
        gather_transform_kernel<<<blocksB, 256, 0, stream>>>(atom_fea, nbr_idx, s, tp_w, out);
    }
}

// Round 2
// 425.324 us; speedup vs baseline: 1.1325x; 1.1060x over previous
//
#include <hip/hip_runtime.h>

#define N_ROWS 100000
#define M_NBR  12
#define C_DIM  64
#define F_DIM  41
#define E_TOT  (N_ROWS * M_NBR)

// ---------------------------------------------------------------------------
// Kernel A: s_e = (softplus(x_e @ W1 + b1) . w2[:,0] + b2[0]) * c
//
// vs round 1: x[41] is force-pinned into VGPRs via empty inline asm after the
// LDS copy (round 1 disclosed VGPR_Count=44 -> compiler had rematerialized
// x[k] as per-iteration ds_reads, re-creating the mixed DS+SMEM lgkmcnt(0)
// drain every 41 FMAs). With x pinned, the hot loop is s_load + v_fmac only:
// one LDS drain up front, SMEM prefetch pipelines under the FMA runs.
// ---------------------------------------------------------------------------
__global__ __launch_bounds__(256) void edge_mlp_kernel(
    const float* __restrict__ nbr_fea,   // [E, F]
    const float* __restrict__ w1,        // [F, F]
    const float* __restrict__ b1,        // [F]
    const float* __restrict__ w2,        // [F, 9]
    const float* __restrict__ b2,        // [9]
    float* __restrict__ s_out)           // [E]
{
    __shared__ float lx[128 * F_DIM];    // 20992 B

    const int tid  = threadIdx.x;
    const long base = (long)blockIdx.x * 256;
    int rem = (int)((long)E_TOT - base);
    const int nedge = rem < 256 ? rem : 256;

    float x[F_DIM];

    // ---- phase 0: stage rows [0,128), threads 0..127 copy their row to regs
    {
        const int cnt = nedge < 128 ? nedge : 128;
        const float* gx = nbr_fea + base * F_DIM;
        const int totf  = cnt * F_DIM;
        const int tot4  = totf >> 2;                 // 16B-aligned (base%256==0)
        const float4* g4 = (const float4*)gx;
        float4* l4 = (float4*)lx;
        for (int i = tid; i < tot4; i += 256) l4[i] = g4[i];
        for (int i = (tot4 << 2) + tid; i < totf; i += 256) lx[i] = gx[i];
        __syncthreads();
        if (tid < cnt) {
            #pragma unroll
            for (int k = 0; k < F_DIM; ++k) x[k] = lx[tid * F_DIM + k];  // stride 41: conflict-free
        }
        __syncthreads();
    }
    // ---- phase 1: stage rows [128,256), threads 128..255 copy to regs
    {
        const int cnt = nedge - 128 < 0 ? 0 : nedge - 128;
        const float* gx = nbr_fea + (base + 128) * F_DIM;   // +20992 B: 16B-aligned
        const int totf  = cnt * F_DIM;
        const int tot4  = totf >> 2;
        const float4* g4 = (const float4*)gx;
        float4* l4 = (float4*)lx;
        for (int i = tid; i < tot4; i += 256) l4[i] = g4[i];
        for (int i = (tot4 << 2) + tid; i < totf; i += 256) lx[i] = gx[i];
        __syncthreads();
        if (tid >= 128 && (tid - 128) < cnt) {
            #pragma unroll
            for (int k = 0; k < F_DIM; ++k) x[k] = lx[(tid - 128) * F_DIM + k];
        }
        __syncthreads();
    }

    if (tid < nedge) {
        // Pin x[] into VGPRs HERE: forces all 41 ds_reads to resolve before
        // the compute loop; compiler cannot rematerialize them inside it.
        #pragma unroll
        for (int k = 0; k < F_DIM; ++k) asm volatile("" : "+v"(x[k]));

        float h[F_DIM];
        #pragma unroll
        for (int j = 0; j < F_DIM; ++j) h[j] = b1[j];          // scalar loads

        #pragma unroll
        for (int k = 0; k < F_DIM; ++k) {                      // FULL unroll: x[k] static
            const float xk = x[k];
            const float* wrow = w1 + k * F_DIM;                // uniform addr -> s_load
            #pragma unroll
            for (int j = 0; j < F_DIM; ++j) h[j] = fmaf(xk, wrow[j], h[j]);
        }

        float acc = b2[0];
        #pragma unroll
        for (int j = 0; j < F_DIM; ++j) {
            float v = h[j];
            float sp = fmaxf(v, 0.0f) + __logf(1.0f + __expf(-fabsf(v)));
            acc = fmaf(sp, w2[j * 9], acc);                    // w2 col 0, scalar loads
        }
        s_out[base + tid] = acc * (0.28209479177387814f / 12.0f);
    }
}

// ---------------------------------------------------------------------------
// Kernel B1: afT = atom_fea @ (tp_w / 8).
//
// vs round 1: the old version streamed all 25.6 MB of atom_fea through the
// SCALAR path (s_load, 16KB K$, out-of-order -> lgkmcnt(0) drains per row).
// Now: stage 64 rows coalesced into LDS (vector path, full BW), then
// wave-uniform ds_read_b128 BROADCAST reads (same addr across lanes = one
// fetch, conflict-free) against per-lane Tc[64] in VGPRs.
// ---------------------------------------------------------------------------
__global__ __launch_bounds__(256) void atom_transform_kernel(
    const float* __restrict__ atom_fea,  // [N, C]
    const float* __restrict__ tp_w,      // [C, C]
    float* __restrict__ afT)             // [N, C]
{
    __shared__ float sA[64 * C_DIM];     // 16 KB: 64 atom rows

    const int tid = threadIdx.x;
    const int c   = tid & 63;
    const int wv  = tid >> 6;

    float Tc[64];
    #pragma unroll
    for (int k = 0; k < 64; ++k) Tc[k] = tp_w[k * 64 + c] * 0.125f;  // coalesced

    const long row0 = (long)blockIdx.x * 64;
    long nrem = (long)N_ROWS - row0;
    const int nrow = nrem < 64 ? (int)nrem : 64;

    // stage nrow rows coalesced: nrow*64 floats, float4 x (nrow*16)
    {
        const float4* g4 = (const float4*)(atom_fea + row0 * C_DIM);
        float4* l4 = (float4*)sA;
        const int tot4 = nrow * 16;
        for (int i = tid; i < tot4; i += 256) l4[i] = g4[i];
    }
    __syncthreads();

    const int r0 = wv * 16;
    for (int i = 0; i < 16; ++i) {
        int rl = r0 + i;                              // wave-uniform
        if (rl >= nrow) break;
        const float4* ar = (const float4*)(sA + rl * C_DIM);   // uniform addr -> ds broadcast
        float o = 0.0f;
        #pragma unroll
        for (int k4 = 0; k4 < 16; ++k4) {
            float4 a = ar[k4];                        // ds_read_b128, broadcast
            o = fmaf(a.x, Tc[4 * k4 + 0], o);
            o = fmaf(a.y, Tc[4 * k4 + 1], o);
            o = fmaf(a.z, Tc[4 * k4 + 2], o);
            o = fmaf(a.w, Tc[4 * k4 + 3], o);
        }
        afT[(row0 + rl) * C_DIM + c] = o;             // coalesced
    }
}

// ---------------------------------------------------------------------------
// Kernel B2: out[r][:] = sum_j s_rj * afT[idx_rj][:].  Pure gather + 12 FMA,
// float4 per lane, 4 rows in flight per wave, no LDS.  (Unchanged this round
// so its counters surface cleanly next round.)
// ---------------------------------------------------------------------------
__global__ __launch_bounds__(256) void gather_kernel(
    const float* __restrict__ afT,       // [N, C]
    const int*   __restrict__ nbr_idx,   // [N, M]
    const float* __restrict__ s,         // [E]
    float* __restrict__ out)             // [N, C]
{
    const int tid  = threadIdx.x;
    const int lane = tid & 63;
    const int wv   = tid >> 6;
    const int q    = lane >> 4;          // row-in-chunk 0..3
    const int c4   = (lane & 15) * 4;    // channel offset

    const int row0 = blockIdx.x * 32 + wv * 8;   // 8 rows per wave (N = 3125*32)

    #pragma unroll
    for (int ch = 0; ch < 2; ++ch) {
        int r = row0 + ch * 4 + q;
        const int*   ir = nbr_idx + r * M_NBR;
        const float* sr = s       + r * M_NBR;
        float4 acc = make_float4(0.f, 0.f, 0.f, 0.f);
        #pragma unroll
        for (int j = 0; j < M_NBR; ++j) {
            int   idx = ir[j];
            float sv  = sr[j];
            const float4 a = *(const float4*)(afT + (long)idx * C_DIM + c4);
            acc.x = fmaf(sv, a.x, acc.x);
            acc.y = fmaf(sv, a.y, acc.y);
            acc.z = fmaf(sv, a.z, acc.z);
            acc.w = fmaf(sv, a.w, acc.w);
        }
        *(float4*)(out + (long)r * C_DIM + c4) = acc;   // coalesced
    }
}

// ---------------------------------------------------------------------------
// Fallback (ws too small for afT): fused gather + LDS-epilogue transform.
// ---------------------------------------------------------------------------
__global__ __launch_bounds__(256) void gather_transform_kernel(
    const float* __restrict__ atom_fea,
    const int*   __restrict__ nbr_idx,
    const float* __restrict__ s,
    const float* __restrict__ tp_w,
    float* __restrict__ out)
{
    __shared__ float accL[64 * C_DIM];
    const int tid = threadIdx.x;
    const int c  = tid & 63;
    const int rq = tid >> 6;

    float Tc[64];
    #pragma unroll
    for (int k = 0; k < 64; ++k) Tc[k] = tp_w[k * 64 + c] * 0.125f;

    const int row0 = blockIdx.x * 64;
    for (int i = 0; i < 16; ++i) {
        int r = row0 + rq * 16 + i;
        float a = 0.0f;
        if (r < N_ROWS) {
            const int*   ir = nbr_idx + (long)r * M_NBR;
            const float* sr = s       + (long)r * M_NBR;
            #pragma unroll
            for (int j = 0; j < M_NBR; ++j)
                a = fmaf(sr[j], atom_fea[(long)ir[j] * C_DIM + c], a);
        }
        accL[(rq * 16 + i) * C_DIM + c] = a;
    }
    __syncthreads();
    for (int i = 0; i < 16; ++i) {
        int rl = rq * 16 + i;
        int r  = row0 + rl;
        if (r >= N_ROWS) continue;
        const float* ar = accL + rl * C_DIM;
        float o = 0.0f;
        #pragma unroll
        for (int k = 0; k < 64; ++k) o = fmaf(ar[k], Tc[k], o);
        out[(long)r * C_DIM + c] = o;
    }
}

extern "C" void kernel_launch(void* const* d_in, const int* in_sizes, int n_in,
                              void* d_out, int out_size, void* d_ws, size_t ws_size,
                              hipStream_t stream) {
    const float* atom_fea = (const float*)d_in[0];
    const float* nbr_fea  = (const float*)d_in[1];
    const int*   nbr_idx  = (const int*)  d_in[2];
    // d_in[3] = pos : dead (only the constant l=0 SH channel couples)
    const float* w1   = (const float*)d_in[4];
    const float* b1   = (const float*)d_in[5];
    const float* w2   = (const float*)d_in[6];
    const float* b2   = (const float*)d_in[7];
    const float* tp_w = (const float*)d_in[8];

    float* s   = (float*)d_ws;                       // 4.8 MB
    float* out = (float*)d_out;

    const int blocksA = (E_TOT + 255) / 256;
    edge_mlp_kernel<<<blocksA, 256, 0, stream>>>(nbr_fea, w1, b1, w2, b2, s);

    const size_t sBytes   = (size_t)E_TOT * sizeof(float);          // 4,800,000 (16B-mult)
    const size_t afTBytes = (size_t)N_ROWS * C_DIM * sizeof(float); // 25.6 MB

    if (ws_size >= sBytes + afTBytes) {
        float* afT = (float*)((char*)d_ws + sBytes);
        const int blocksT = (N_ROWS + 63) / 64;
        atom_transform_kernel<<<blocksT, 256, 0, stream>>>(atom_fea, tp_w, afT);
        const int blocksG = N_ROWS / 32;             // 3125, exact
        gather_kernel<<<blocksG, 256, 0, stream>>>(afT, nbr_idx, s, out);
    } else {
        const int blocksB = (N_ROWS + 63) / 64;
        gather_transform_kernel<<<blocksB, 256, 0, stream>>>(atom_fea, nbr_idx, s, tp_w, out);
    }
}